// Round 1
// baseline (3577.258 us; speedup 1.0000x reference)
//
#include <hip/hip_runtime.h>
#include <hip/hip_bf16.h>

// Problem constants
#define BB   16
#define LL   50
#define PP   49
#define TT   20
#define DD   512
#define HH   8
#define DHH  64
#define DFF  2048

#define BL     (BB*LL)          // 800
#define ROWS_I (BL*TT)          // 16000  (img-branch rows, i.e. out_img rows)
#define ROWS_T (BL*PP)          // 39200  (tit-branch rows)
#define ROWS_A (ROWS_I+ROWS_T)  // 55200
#define OUT_I_ELEMS ((size_t)ROWS_I*DD)   // 8,192,000
// ws layout:
//   phase1: hidpre fp32 [0 .. 28,262,400 floats)               (113.0 MB)
//   phase2: act bf16    [0 .. 39200*2048)                      (160.6 MB)
//           f2  fp32    [byte 160,563,200 .. +80,281,600)      ( 80.3 MB)
// total ws required: 240,844,800 bytes
#define F2_BYTE_OFF (39200ull*2048ull*2ull)

__device__ __forceinline__ float bf2f(unsigned short u) {
    union { unsigned int i; float f; } w; w.i = ((unsigned int)u) << 16; return w.f;
}
__device__ __forceinline__ unsigned short f2bf(float f) {
    union { float f; unsigned int i; } w; w.f = f;
    unsigned int x = w.i;
    unsigned int r = (x + 0x7fffu + ((x >> 16) & 1u)) >> 16;
    return (unsigned short)r;
}
__device__ __forceinline__ float gelu_tanh_f(float x) {
    float c = 0.7978845608028654f * (x + 0.044715f * x * x * x);
    return 0.5f * x * (1.0f + tanhf(c));
}

// ---------------------------------------------------------------------------
// Attention: one block per (bl, h). Writes pre-proj hid into ws:
//   hid_img at hid[(bl*TT+t)*DD + h*64 + d]
//   hid_tit at hid[OUT_I_ELEMS + (bl*PP+p)*DD + h*64 + d]
// ---------------------------------------------------------------------------
__global__ __launch_bounds__(256) void attn_kernel(
    const float* __restrict__ img, const float* __restrict__ title,
    const int* __restrict__ mask, const float* __restrict__ scale_img,
    const float* __restrict__ scale_tit, float* __restrict__ hid)
{
    const int blh = blockIdx.x;
    const int h  = blh & 7;
    const int bl = blh >> 3;
    const int tid = threadIdx.x;

    __shared__ float simg[PP][DHH + 1];
    __shared__ float stit[TT][DHH + 1];
    __shared__ float S [PP][TT];
    __shared__ float pI[PP][TT];   // softmax over t, per p
    __shared__ float pT[TT][PP];   // softmax over p, per t
    __shared__ int   msk[TT];

    const float* imgbase = img   + (size_t)bl * PP * DD + h * DHH;
    const float* titbase = title + (size_t)bl * TT * DD + h * DHH;
    for (int i = tid; i < PP * DHH; i += 256) {
        int p = i >> 6, d = i & 63;
        simg[p][d] = imgbase[(size_t)p * DD + d];
    }
    for (int i = tid; i < TT * DHH; i += 256) {
        int t = i >> 6, d = i & 63;
        stit[t][d] = titbase[(size_t)t * DD + d];
    }
    if (tid < TT) msk[tid] = mask[bl * TT + tid];
    __syncthreads();

    // S[p][t] = (1/8) * dot64(img_p, tit_t)
    for (int i = tid; i < PP * TT; i += 256) {
        int p = i / TT, t = i % TT;
        float s = 0.f;
        #pragma unroll 8
        for (int d = 0; d < DHH; ++d) s += simg[p][d] * stit[t][d];
        S[p][t] = s * 0.125f;
    }
    __syncthreads();

    // p_img: per p, softmax over t of S[p][t]*scale_img[h,p] with mask on t
    if (tid < PP) {
        const int p = tid;
        const float sc = scale_img[h * PP + p];
        float m = -1e30f;
        #pragma unroll
        for (int t = 0; t < TT; ++t) {
            float x = (msk[t] == 0) ? -1e9f : S[p][t] * sc;
            m = fmaxf(m, x);
        }
        float sum = 0.f;
        #pragma unroll
        for (int t = 0; t < TT; ++t) {
            float x = (msk[t] == 0) ? -1e9f : S[p][t] * sc;
            float e = __expf(x - m);
            pI[p][t] = e; sum += e;
        }
        float inv = 1.f / sum;
        #pragma unroll
        for (int t = 0; t < TT; ++t) pI[p][t] *= inv;
    }
    // p_tit: per t, softmax over p of S[p][t]*scale_title[h,t]; whole row dead if mask[t]==0
    if (tid >= 64 && tid < 64 + TT) {
        const int t = tid - 64;
        const float sc = scale_tit[h * TT + t];
        const bool dead = (msk[t] == 0);
        float m = -1e30f;
        #pragma unroll
        for (int p = 0; p < PP; ++p) {
            float x = dead ? -1e9f : S[p][t] * sc;
            m = fmaxf(m, x);
        }
        float sum = 0.f;
        #pragma unroll
        for (int p = 0; p < PP; ++p) {
            float x = dead ? -1e9f : S[p][t] * sc;
            float e = __expf(x - m);
            pT[t][p] = e; sum += e;
        }
        float inv = 1.f / sum;
        #pragma unroll
        for (int p = 0; p < PP; ++p) pT[t][p] *= inv;
    }
    __syncthreads();

    // hid_img[t][d] = sum_p pT[t][p] * simg[p][d]
    for (int i = tid; i < TT * DHH; i += 256) {
        int t = i >> 6, d = i & 63;
        float s = 0.f;
        #pragma unroll
        for (int p = 0; p < PP; ++p) s += pT[t][p] * simg[p][d];
        hid[(size_t)(bl * TT + t) * DD + h * DHH + d] = s;
    }
    // hid_tit[p][d] = sum_t pI[p][t] * stit[t][d]
    for (int i = tid; i < PP * DHH; i += 256) {
        int p = i >> 6, d = i & 63;
        float s = 0.f;
        #pragma unroll
        for (int t = 0; t < TT; ++t) s += pI[p][t] * stit[t][d];
        hid[OUT_I_ELEMS + (size_t)(bl * PP + p) * DD + h * DHH + d] = s;
    }
}

// ---------------------------------------------------------------------------
// GEMM  C[M,N] = A[M,K] @ B[N,K]^T + bias[N]   (both K-contiguous)
// 128x128 tile, 256 threads, 8x8 microtile, BK=8.
// TA: float or ushort(bf16 bits). OUT_BF16: store bf16, else fp32. GELU epilogue opt.
// ---------------------------------------------------------------------------
template<typename TA, bool GELU, bool OUT_BF16>
__global__ __launch_bounds__(256) void gemm_nt(
    const void* __restrict__ Av, const float* __restrict__ B,
    const float* __restrict__ bias, void* __restrict__ Cv,
    int M, int N, int K)
{
    const TA* A = (const TA*)Av;
    __shared__ float As[8][128];
    __shared__ float Bs[8][128];
    const int tid = threadIdx.x;
    const int row0 = blockIdx.y * 128;
    const int col0 = blockIdx.x * 128;
    const int tx = tid & 15;      // n-dir
    const int ty = tid >> 4;      // m-dir
    const int lr = tid >> 1;      // 0..127 (load row)
    const int lk = (tid & 1) * 4; // 0 or 4

    float acc[8][8];
    #pragma unroll
    for (int i = 0; i < 8; ++i)
        #pragma unroll
        for (int j = 0; j < 8; ++j) acc[i][j] = 0.f;

    for (int k0 = 0; k0 < K; k0 += 8) {
        // A tile (guard rows)
        {
            const int gr = row0 + lr;
            float v0 = 0.f, v1 = 0.f, v2 = 0.f, v3 = 0.f;
            if (gr < M) {
                const TA* src = A + (size_t)gr * K + k0 + lk;
                if constexpr (sizeof(TA) == 4) {
                    float4 v = *(const float4*)src;
                    v0 = v.x; v1 = v.y; v2 = v.z; v3 = v.w;
                } else {
                    ushort4 u = *(const ushort4*)src;
                    v0 = bf2f(u.x); v1 = bf2f(u.y); v2 = bf2f(u.z); v3 = bf2f(u.w);
                }
            }
            As[lk + 0][lr] = v0; As[lk + 1][lr] = v1;
            As[lk + 2][lr] = v2; As[lk + 3][lr] = v3;
        }
        // B tile (N always multiple of 128 here)
        {
            const int gc = col0 + lr;
            float4 v = *(const float4*)(B + (size_t)gc * K + k0 + lk);
            Bs[lk + 0][lr] = v.x; Bs[lk + 1][lr] = v.y;
            Bs[lk + 2][lr] = v.z; Bs[lk + 3][lr] = v.w;
        }
        __syncthreads();
        #pragma unroll
        for (int kk = 0; kk < 8; ++kk) {
            float4 a0 = *(const float4*)&As[kk][ty * 8];
            float4 a1 = *(const float4*)&As[kk][ty * 8 + 4];
            float4 b0 = *(const float4*)&Bs[kk][tx * 8];
            float4 b1 = *(const float4*)&Bs[kk][tx * 8 + 4];
            float a[8] = {a0.x,a0.y,a0.z,a0.w,a1.x,a1.y,a1.z,a1.w};
            float b[8] = {b0.x,b0.y,b0.z,b0.w,b1.x,b1.y,b1.z,b1.w};
            #pragma unroll
            for (int i = 0; i < 8; ++i)
                #pragma unroll
                for (int j = 0; j < 8; ++j)
                    acc[i][j] = fmaf(a[i], b[j], acc[i][j]);
        }
        __syncthreads();
    }

    #pragma unroll
    for (int i = 0; i < 8; ++i) {
        const int r = row0 + ty * 8 + i;
        if (r >= M) break;
        #pragma unroll
        for (int j = 0; j < 8; ++j) {
            const int c = col0 + tx * 8 + j;
            float v = acc[i][j] + bias[c];
            if (GELU) v = gelu_tanh_f(v);
            if (OUT_BF16) ((unsigned short*)Cv)[(size_t)r * N + c] = f2bf(v);
            else          ((float*)Cv)[(size_t)r * N + c] = v;
        }
    }
}

// ---------------------------------------------------------------------------
// Residual + LayerNorm (ddof=1):  out[row] = out[row] + a*(x-mean)/(std+eps)+b
// One wave (64 lanes) per row of 512; 4 rows per block.
// ---------------------------------------------------------------------------
__global__ __launch_bounds__(256) void ln_res_kernel(
    const float* __restrict__ f2, float* __restrict__ out,
    const float* __restrict__ a, const float* __restrict__ b, int M)
{
    const int wave = threadIdx.x >> 6;
    const int lane = threadIdx.x & 63;
    const int row = blockIdx.x * 4 + wave;
    if (row >= M) return;
    const float* x = f2 + (size_t)row * DD;
    float* o = out + (size_t)row * DD;

    float xs[8];
    float s1 = 0.f, s2 = 0.f;
    #pragma unroll
    for (int i = 0; i < 8; ++i) {
        float v = x[lane + i * 64];
        xs[i] = v; s1 += v; s2 += v * v;
    }
    #pragma unroll
    for (int off = 32; off > 0; off >>= 1) {
        s1 += __shfl_xor(s1, off, 64);
        s2 += __shfl_xor(s2, off, 64);
    }
    const float mean = s1 * (1.f / 512.f);
    float var = (s2 - 512.f * mean * mean) * (1.f / 511.f);
    var = fmaxf(var, 0.f);
    const float rinv = 1.f / (sqrtf(var) + 1e-6f);
    #pragma unroll
    for (int i = 0; i < 8; ++i) {
        const int d = lane + i * 64;
        o[d] = o[d] + a[d] * (xs[i] - mean) * rinv + b[d];
    }
}

// ---------------------------------------------------------------------------
extern "C" void kernel_launch(void* const* d_in, const int* in_sizes, int n_in,
                              void* d_out, int out_size, void* d_ws, size_t ws_size,
                              hipStream_t stream) {
    const float* img       = (const float*)d_in[0];
    const float* title     = (const float*)d_in[1];
    const int*   mask      = (const int*)  d_in[2];
    const float* scale_img = (const float*)d_in[3];
    const float* scale_tit = (const float*)d_in[4];
    const float* w_proj    = (const float*)d_in[5];
    const float* b_proj    = (const float*)d_in[6];
    const float* w1_img    = (const float*)d_in[7];
    const float* b1_img    = (const float*)d_in[8];
    const float* w2_img    = (const float*)d_in[9];
    const float* b2_img    = (const float*)d_in[10];
    const float* w1_tit    = (const float*)d_in[11];
    const float* b1_tit    = (const float*)d_in[12];
    const float* w2_tit    = (const float*)d_in[13];
    const float* b2_tit    = (const float*)d_in[14];
    const float* ln_a_img  = (const float*)d_in[15];
    const float* ln_b_img  = (const float*)d_in[16];
    const float* ln_a_tit  = (const float*)d_in[17];
    const float* ln_b_tit  = (const float*)d_in[18];

    float* out = (float*)d_out;
    float* hidpre = (float*)d_ws;                                // phase 1
    unsigned short* act = (unsigned short*)d_ws;                 // phase 2 (bf16)
    float* f2 = (float*)((char*)d_ws + F2_BYTE_OFF);             // phase 2

    // 1) attention -> pre-proj hid in ws (concat img rows then tit rows)
    attn_kernel<<<BL * HH, 256, 0, stream>>>(img, title, mask, scale_img, scale_tit, hidpre);

    // 2) shared projection over all 55200 rows: ws -> d_out
    gemm_nt<float, false, false><<<dim3(DD / 128, (ROWS_A + 127) / 128), 256, 0, stream>>>(
        hidpre, w_proj, b_proj, out, ROWS_A, DD, DD);

    // 3) img branch FFN + LN
    gemm_nt<float, true, true><<<dim3(DFF / 128, (ROWS_I + 127) / 128), 256, 0, stream>>>(
        out, w1_img, b1_img, act, ROWS_I, DFF, DD);
    gemm_nt<unsigned short, false, false><<<dim3(DD / 128, (ROWS_I + 127) / 128), 256, 0, stream>>>(
        act, w2_img, b2_img, f2, ROWS_I, DD, DFF);
    ln_res_kernel<<<(ROWS_I + 3) / 4, 256, 0, stream>>>(f2, out, ln_a_img, ln_b_img, ROWS_I);

    // 4) tit branch FFN + LN
    gemm_nt<float, true, true><<<dim3(DFF / 128, (ROWS_T + 127) / 128), 256, 0, stream>>>(
        out + OUT_I_ELEMS, w1_tit, b1_tit, act, ROWS_T, DFF, DD);
    gemm_nt<unsigned short, false, false><<<dim3(DD / 128, (ROWS_T + 127) / 128), 256, 0, stream>>>(
        act, w2_tit, b2_tit, f2, ROWS_T, DD, DFF);
    ln_res_kernel<<<(ROWS_T + 3) / 4, 256, 0, stream>>>(f2, out + OUT_I_ELEMS, ln_a_tit, ln_b_tit, ROWS_T);
}

// Round 2
// 946.262 us; speedup vs baseline: 3.7804x; 3.7804x over previous
//
#include <hip/hip_runtime.h>
#include <hip/hip_bf16.h>

// Problem constants
#define BB   16
#define LL   50
#define PP   49
#define TT   20
#define DD   512
#define HH   8
#define DHH  64
#define DFF  2048

#define BL     (BB*LL)          // 800
#define ROWS_I (BL*TT)          // 16000
#define ROWS_T (BL*PP)          // 39200
#define ROWS_A (ROWS_I+ROWS_T)  // 55200
#define OUT_I_ELEMS ((size_t)ROWS_I*DD)
#define CHUNK 19600             // tit branch processed in 2 chunks

// ws layout (bytes) — total 185,860,096 (< proven 240 MB)
//  R0 act/hid : [0, 80,281,600)            act bf16 (<=19600x2048); hid bf16 (55200x512) early
//  R1 out_bf16: [80,281,600, +56,524,800)
//  R2 f2 fp32 : [136,806,400, +40,140,800)
//  R3 weights : [176,947,200, +8,912,896)
#define R1_OFF 80281600ull
#define R2_OFF 136806400ull
#define R3_OFF 176947200ull

typedef __attribute__((ext_vector_type(8))) short bf16x8;
typedef __attribute__((ext_vector_type(4))) float f32x4;

__device__ __forceinline__ unsigned short f2bf(float f) {
    union { float f; unsigned int i; } w; w.f = f;
    unsigned int x = w.i;
    unsigned int r = (x + 0x7fffu + ((x >> 16) & 1u)) >> 16;
    return (unsigned short)r;
}
__device__ __forceinline__ float gelu_tanh_f(float x) {
    float c = 0.7978845608028654f * (x + 0.044715f * x * x * x);
    return 0.5f * x * (1.0f + tanhf(c));
}

// ---------------------------------------------------------------------------
// fp32 -> bf16 convert (n4 = n/4)
// ---------------------------------------------------------------------------
__global__ __launch_bounds__(256) void cvt_kernel(
    const float* __restrict__ s, unsigned short* __restrict__ d, int n4)
{
    int i = blockIdx.x * 256 + threadIdx.x;
    if (i < n4) {
        float4 v = ((const float4*)s)[i];
        ushort4 u;
        u.x = f2bf(v.x); u.y = f2bf(v.y); u.z = f2bf(v.z); u.w = f2bf(v.w);
        ((ushort4*)d)[i] = u;
    }
}

// ---------------------------------------------------------------------------
// Attention: one block per (bl, h). Writes pre-proj hid (bf16) into ws:
//   hid_img rows [0,16000), hid_tit rows [16000,55200)
// ---------------------------------------------------------------------------
__global__ __launch_bounds__(256) void attn_kernel(
    const float* __restrict__ img, const float* __restrict__ title,
    const int* __restrict__ mask, const float* __restrict__ scale_img,
    const float* __restrict__ scale_tit, unsigned short* __restrict__ hid)
{
    const int blh = blockIdx.x;
    const int h  = blh & 7;
    const int bl = blh >> 3;
    const int tid = threadIdx.x;

    __shared__ float simg[PP][DHH + 1];
    __shared__ float stit[TT][DHH + 1];
    __shared__ float S [PP][TT];
    __shared__ float pI[PP][TT];
    __shared__ float pT[TT][PP];
    __shared__ int   msk[TT];

    const float* imgbase = img   + (size_t)bl * PP * DD + h * DHH;
    const float* titbase = title + (size_t)bl * TT * DD + h * DHH;
    for (int i = tid; i < PP * DHH; i += 256) {
        int p = i >> 6, d = i & 63;
        simg[p][d] = imgbase[(size_t)p * DD + d];
    }
    for (int i = tid; i < TT * DHH; i += 256) {
        int t = i >> 6, d = i & 63;
        stit[t][d] = titbase[(size_t)t * DD + d];
    }
    if (tid < TT) msk[tid] = mask[bl * TT + tid];
    __syncthreads();

    for (int i = tid; i < PP * TT; i += 256) {
        int p = i / TT, t = i % TT;
        float s = 0.f;
        #pragma unroll 8
        for (int d = 0; d < DHH; ++d) s += simg[p][d] * stit[t][d];
        S[p][t] = s * 0.125f;
    }
    __syncthreads();

    if (tid < PP) {
        const int p = tid;
        const float sc = scale_img[h * PP + p];
        float m = -1e30f;
        #pragma unroll
        for (int t = 0; t < TT; ++t) {
            float x = (msk[t] == 0) ? -1e9f : S[p][t] * sc;
            m = fmaxf(m, x);
        }
        float sum = 0.f;
        #pragma unroll
        for (int t = 0; t < TT; ++t) {
            float x = (msk[t] == 0) ? -1e9f : S[p][t] * sc;
            float e = __expf(x - m);
            pI[p][t] = e; sum += e;
        }
        float inv = 1.f / sum;
        #pragma unroll
        for (int t = 0; t < TT; ++t) pI[p][t] *= inv;
    }
    if (tid >= 64 && tid < 64 + TT) {
        const int t = tid - 64;
        const float sc = scale_tit[h * TT + t];
        const bool dead = (msk[t] == 0);
        float m = -1e30f;
        #pragma unroll
        for (int p = 0; p < PP; ++p) {
            float x = dead ? -1e9f : S[p][t] * sc;
            m = fmaxf(m, x);
        }
        float sum = 0.f;
        #pragma unroll
        for (int p = 0; p < PP; ++p) {
            float x = dead ? -1e9f : S[p][t] * sc;
            float e = __expf(x - m);
            pT[t][p] = e; sum += e;
        }
        float inv = 1.f / sum;
        #pragma unroll
        for (int p = 0; p < PP; ++p) pT[t][p] *= inv;
    }
    __syncthreads();

    for (int i = tid; i < TT * DHH; i += 256) {
        int t = i >> 6, d = i & 63;
        float s = 0.f;
        #pragma unroll
        for (int p = 0; p < PP; ++p) s += pT[t][p] * simg[p][d];
        hid[(size_t)(bl * TT + t) * DD + h * DHH + d] = f2bf(s);
    }
    for (int i = tid; i < PP * DHH; i += 256) {
        int p = i >> 6, d = i & 63;
        float s = 0.f;
        #pragma unroll
        for (int t = 0; t < TT; ++t) s += pI[p][t] * stit[t][d];
        hid[OUT_I_ELEMS + (size_t)(bl * PP + p) * DD + h * DHH + d] = f2bf(s);
    }
}

// ---------------------------------------------------------------------------
// MFMA GEMM: C[M,N] = A[M,K](bf16) @ Bw[N,K](bf16)^T + bias[N]
// 128x128 tile, BK=32, 256 thr = 4 waves (2x2 of 64x64), mfma_f32_16x16x32_bf16.
// global_load_lds width-16 staging; unpadded [row][32] LDS layout (lane-ordered).
// Row-tail: reads clamped, stores guarded. N, K multiples of 128/32.
// ---------------------------------------------------------------------------
template<bool GELU, bool F32OUT, bool BF16OUT>
__global__ __launch_bounds__(256) void gemm_mfma(
    const unsigned short* __restrict__ A, const unsigned short* __restrict__ Bw,
    const float* __restrict__ bias,
    float* __restrict__ Cf, unsigned short* __restrict__ Cb,
    int M, int N, int K)
{
    __shared__ unsigned short As[128 * 32];
    __shared__ unsigned short Bs[128 * 32];
    const int tid  = threadIdx.x;
    const int wave = tid >> 6;
    const int lane = tid & 63;
    const int row0 = blockIdx.y * 128;
    const int col0 = blockIdx.x * 128;
    const int m_off = (wave >> 1) * 64;
    const int n_off = (wave & 1) * 64;
    const int lane_m = lane & 15;
    const int lane_k = (lane >> 4) * 8;

    f32x4 acc[4][4] = {};

    for (int k0 = 0; k0 < K; k0 += 32) {
        #pragma unroll
        for (int q = 0; q < 2; ++q) {
            const int li = q * 256 + tid;
            int gr = row0 + (li >> 2);
            if (gr >= M) gr = M - 1;                     // clamp (store-guarded later)
            const unsigned short* gp = A + (size_t)gr * K + k0 + (li & 3) * 8;
            __builtin_amdgcn_global_load_lds(
                (const __attribute__((address_space(1))) unsigned int*)gp,
                (__attribute__((address_space(3))) unsigned int*)&As[li * 8], 16, 0, 0);
        }
        #pragma unroll
        for (int q = 0; q < 2; ++q) {
            const int li = q * 256 + tid;
            const unsigned short* gp = Bw + (size_t)(col0 + (li >> 2)) * K + k0 + (li & 3) * 8;
            __builtin_amdgcn_global_load_lds(
                (const __attribute__((address_space(1))) unsigned int*)gp,
                (__attribute__((address_space(3))) unsigned int*)&Bs[li * 8], 16, 0, 0);
        }
        __syncthreads();

        bf16x8 af[4], bf[4];
        #pragma unroll
        for (int i = 0; i < 4; ++i) {
            af[i] = *(const bf16x8*)&As[(m_off + i * 16 + lane_m) * 32 + lane_k];
            bf[i] = *(const bf16x8*)&Bs[(n_off + i * 16 + lane_m) * 32 + lane_k];
        }
        #pragma unroll
        for (int i = 0; i < 4; ++i)
            #pragma unroll
            for (int j = 0; j < 4; ++j)
                acc[i][j] = __builtin_amdgcn_mfma_f32_16x16x32_bf16(af[i], bf[j], acc[i][j], 0, 0, 0);
        __syncthreads();
    }

    // Epilogue. C/D layout: col = lane&15, row = (lane>>4)*4 + reg
    #pragma unroll
    for (int i = 0; i < 4; ++i) {
        #pragma unroll
        for (int r = 0; r < 4; ++r) {
            const int row = row0 + m_off + i * 16 + (lane >> 4) * 4 + r;
            if (row < M) {
                #pragma unroll
                for (int j = 0; j < 4; ++j) {
                    const int col = col0 + n_off + j * 16 + lane_m;
                    float v = acc[i][j][r] + bias[col];
                    if (GELU) v = gelu_tanh_f(v);
                    if (F32OUT)  Cf[(size_t)row * N + col] = v;
                    if (BF16OUT) Cb[(size_t)row * N + col] = f2bf(v);
                }
            }
        }
    }
}

// ---------------------------------------------------------------------------
// Residual + LayerNorm (ddof=1): out[row] += a*(x-mean)/(std+eps)+b
// ---------------------------------------------------------------------------
__global__ __launch_bounds__(256) void ln_res_kernel(
    const float* __restrict__ f2, float* __restrict__ out,
    const float* __restrict__ a, const float* __restrict__ b, int M)
{
    const int wave = threadIdx.x >> 6;
    const int lane = threadIdx.x & 63;
    const int row = blockIdx.x * 4 + wave;
    if (row >= M) return;
    const float* x = f2 + (size_t)row * DD;
    float* o = out + (size_t)row * DD;

    float xs[8];
    float s1 = 0.f, s2 = 0.f;
    #pragma unroll
    for (int i = 0; i < 8; ++i) {
        float v = x[lane + i * 64];
        xs[i] = v; s1 += v; s2 += v * v;
    }
    #pragma unroll
    for (int off = 32; off > 0; off >>= 1) {
        s1 += __shfl_xor(s1, off, 64);
        s2 += __shfl_xor(s2, off, 64);
    }
    const float mean = s1 * (1.f / 512.f);
    float var = (s2 - 512.f * mean * mean) * (1.f / 511.f);
    var = fmaxf(var, 0.f);
    const float rinv = 1.f / (sqrtf(var) + 1e-6f);
    #pragma unroll
    for (int i = 0; i < 8; ++i) {
        const int d = lane + i * 64;
        o[d] = o[d] + a[d] * (xs[i] - mean) * rinv + b[d];
    }
}

// ---------------------------------------------------------------------------
extern "C" void kernel_launch(void* const* d_in, const int* in_sizes, int n_in,
                              void* d_out, int out_size, void* d_ws, size_t ws_size,
                              hipStream_t stream) {
    const float* img       = (const float*)d_in[0];
    const float* title     = (const float*)d_in[1];
    const int*   mask      = (const int*)  d_in[2];
    const float* scale_img = (const float*)d_in[3];
    const float* scale_tit = (const float*)d_in[4];
    const float* w_proj    = (const float*)d_in[5];
    const float* b_proj    = (const float*)d_in[6];
    const float* w1_img    = (const float*)d_in[7];
    const float* b1_img    = (const float*)d_in[8];
    const float* w2_img    = (const float*)d_in[9];
    const float* b2_img    = (const float*)d_in[10];
    const float* w1_tit    = (const float*)d_in[11];
    const float* b1_tit    = (const float*)d_in[12];
    const float* w2_tit    = (const float*)d_in[13];
    const float* b2_tit    = (const float*)d_in[14];
    const float* ln_a_img  = (const float*)d_in[15];
    const float* ln_b_img  = (const float*)d_in[16];
    const float* ln_a_tit  = (const float*)d_in[17];
    const float* ln_b_tit  = (const float*)d_in[18];

    float* out = (float*)d_out;
    unsigned short* hid_bf = (unsigned short*)d_ws;                       // R0 (early)
    unsigned short* act    = (unsigned short*)d_ws;                       // R0 (late)
    unsigned short* out_bf = (unsigned short*)((char*)d_ws + R1_OFF);     // R1
    float*          f2     = (float*)((char*)d_ws + R2_OFF);              // R2
    unsigned short* wp_bf  = (unsigned short*)((char*)d_ws + R3_OFF);     // R3
    unsigned short* w1i_bf = wp_bf  + 262144;
    unsigned short* w2i_bf = w1i_bf + 1048576;
    unsigned short* w1t_bf = w2i_bf + 1048576;
    unsigned short* w2t_bf = w1t_bf + 1048576;

    // 0) weights -> bf16
    cvt_kernel<<<(262144/4 + 255)/256, 256, 0, stream>>>(w_proj, wp_bf, 262144/4);
    cvt_kernel<<<(1048576/4 + 255)/256, 256, 0, stream>>>(w1_img, w1i_bf, 1048576/4);
    cvt_kernel<<<(1048576/4 + 255)/256, 256, 0, stream>>>(w2_img, w2i_bf, 1048576/4);
    cvt_kernel<<<(1048576/4 + 255)/256, 256, 0, stream>>>(w1_tit, w1t_bf, 1048576/4);
    cvt_kernel<<<(1048576/4 + 255)/256, 256, 0, stream>>>(w2_tit, w2t_bf, 1048576/4);

    // 1) attention -> hid_bf (bf16)
    attn_kernel<<<BL * HH, 256, 0, stream>>>(img, title, mask, scale_img, scale_tit, hid_bf);

    // 2) proj over all 55200 rows: fp32 -> d_out, bf16 copy -> out_bf
    gemm_mfma<false, true, true><<<dim3(DD/128, (ROWS_A + 127)/128), 256, 0, stream>>>(
        hid_bf, wp_bf, b_proj, out, out_bf, ROWS_A, DD, DD);

    // 3) img branch (16000 rows, one chunk)
    gemm_mfma<true, false, true><<<dim3(DFF/128, (ROWS_I + 127)/128), 256, 0, stream>>>(
        out_bf, w1i_bf, b1_img, nullptr, act, ROWS_I, DFF, DD);
    gemm_mfma<false, true, false><<<dim3(DD/128, (ROWS_I + 127)/128), 256, 0, stream>>>(
        act, w2i_bf, b2_img, f2, nullptr, ROWS_I, DD, DFF);
    ln_res_kernel<<<(ROWS_I + 3)/4, 256, 0, stream>>>(f2, out, ln_a_img, ln_b_img, ROWS_I);

    // 4) tit branch (39200 rows, two chunks of 19600)
    for (int c = 0; c < 2; ++c) {
        const unsigned short* a1 = out_bf + (size_t)(ROWS_I + c * CHUNK) * DD;
        float* o1 = out + OUT_I_ELEMS + (size_t)c * CHUNK * DD;
        gemm_mfma<true, false, true><<<dim3(DFF/128, (CHUNK + 127)/128), 256, 0, stream>>>(
            a1, w1t_bf, b1_tit, nullptr, act, CHUNK, DFF, DD);
        gemm_mfma<false, true, false><<<dim3(DD/128, (CHUNK + 127)/128), 256, 0, stream>>>(
            act, w2t_bf, b2_tit, f2, nullptr, CHUNK, DD, DFF);
        ln_res_kernel<<<(CHUNK + 3)/4, 256, 0, stream>>>(f2, o1, ln_a_tit, ln_b_tit, CHUNK);
    }
}